// Round 10
// baseline (149.185 us; speedup 1.0000x reference)
//
#include <hip/hip_runtime.h>
#include <math.h>

#define NPOS   1024
#define CIN    256
#define DQKV   1536
#define ATTND  512
#define HEADS  8
#define DH     64
#define COUT   256
#define NBATCH 8
#define SCALE  0.125f
#define GN_EPS 1e-5f

typedef __attribute__((ext_vector_type(8))) __bf16 bf16x8;
typedef __attribute__((ext_vector_type(4))) __bf16 bf16x4;
typedef __attribute__((ext_vector_type(4))) float floatx4;
typedef __attribute__((ext_vector_type(8))) unsigned short ushort8;

// ws byte layout:
//   wT    bf16 [1536][256]          @ 4 MiB          (SCALE folded into cols<512)
//   woT   bf16 [256][512]           @ 4.75 MiB
//   qb    bf16 [B][H][1024][64]     @ 5 MiB
//   kb    bf16 same                 @ 13 MiB
//   vT    bf16 [B][H][64][1024]     @ 29 MiB         (written directly by qkv)
//   o2tT  bf16 [B][1024][512]       @ 45 MiB         (un-scrambled: [b][p][ch])
//   stats fp32 [256]                @ 53 MiB   sum[b]@b*16, sq[b]@128+b*16, counter@192
#define OFF_WT   (4ull*1048576)
#define OFF_WOT  (4ull*1048576 + 786432ull)
#define OFF_QB   (5ull*1048576)
#define OFF_KB   (13ull*1048576)
#define OFF_VT   (29ull*1048576)
#define OFF_O2TT (45ull*1048576)
#define OFF_ST   (53ull*1048576)

__device__ inline ushort8 cvt_bf8(float4 a, float4 b) {
    bf16x8 o;
    o[0] = (__bf16)a.x; o[1] = (__bf16)a.y; o[2] = (__bf16)a.z; o[3] = (__bf16)a.w;
    o[4] = (__bf16)b.x; o[5] = (__bf16)b.y; o[6] = (__bf16)b.z; o[7] = (__bf16)b.w;
    return *(ushort8*)&o;
}

// ---------------- prep: weight conversions only (+ zero stats/counter) ----------------
// grid 128: [0,96) w_qkv -> wT; [96,128) w_out -> woT.
__global__ __launch_bounds__(256) void prep(
    const float* __restrict__ w_qkv, const float* __restrict__ w_out,
    unsigned short* __restrict__ wT, unsigned short* __restrict__ woT,
    float* __restrict__ stats)
{
    const int bid = blockIdx.x;
    const int t = threadIdx.x;
    __shared__ unsigned short tile[64][68];

    if (bid == 0) stats[t] = 0.0f;

    if (bid < 96) {
        const int n0 = (bid >> 2) * 64, k0 = (bid & 3) * 64;
        #pragma unroll
        for (int p = 0; p < 4; ++p) {
            const int row = p * 16 + (t >> 4);
            const int c = (t & 15) * 4;
            float4 a = *(const float4*)&w_qkv[(size_t)(k0 + row) * DQKV + n0 + c];
            float sv[4] = {a.x, a.y, a.z, a.w};
            #pragma unroll
            for (int j = 0; j < 4; ++j) {
                const float sc = (n0 + c + j) < 512 ? SCALE : 1.0f;
                __bf16 hb = (__bf16)(sv[j] * sc);
                tile[row][c + j] = *(unsigned short*)&hb;
            }
        }
        __syncthreads();
        const int nn = t >> 2;
        const int kc = (t & 3) * 16;
        unsigned short tmp[16];
        #pragma unroll
        for (int j = 0; j < 16; ++j) tmp[j] = tile[kc + j][nn];
        *(ushort8*)&wT[(size_t)(n0 + nn) * 256 + k0 + kc]     = *(ushort8*)&tmp[0];
        *(ushort8*)&wT[(size_t)(n0 + nn) * 256 + k0 + kc + 8] = *(ushort8*)&tmp[8];
        return;
    }

    const int idx = bid - 96;
    const int d0 = (idx & 3) * 64, k0 = (idx >> 2) * 64;
    #pragma unroll
    for (int p = 0; p < 4; ++p) {
        const int row = p * 16 + (t >> 4);
        const int c = (t & 15) * 4;
        float4 a = *(const float4*)&w_out[(size_t)(k0 + row) * COUT + d0 + c];
        float sv[4] = {a.x, a.y, a.z, a.w};
        #pragma unroll
        for (int j = 0; j < 4; ++j) {
            __bf16 hb = (__bf16)sv[j];
            tile[row][c + j] = *(unsigned short*)&hb;
        }
    }
    __syncthreads();
    {
        const int nn = t >> 2;
        const int kc = (t & 3) * 16;
        unsigned short tmp[16];
        #pragma unroll
        for (int j = 0; j < 16; ++j) tmp[j] = tile[kc + j][nn];
        *(ushort8*)&woT[(size_t)(d0 + nn) * 512 + k0 + kc]     = *(ushort8*)&tmp[0];
        *(ushort8*)&woT[(size_t)(d0 + nn) * 512 + k0 + kc + 8] = *(ushort8*)&tmp[8];
    }
}

// ---------------- kernel A: QKV GEMM, bf16 MFMA, fused x-conversion + V transpose ----------------
__global__ __launch_bounds__(256) void qkv_gemm_mfma(
    const float* __restrict__ x, const __bf16* __restrict__ wT,
    __bf16* __restrict__ qb, __bf16* __restrict__ kb, __bf16* __restrict__ vT)
{
    const int t = threadIdx.x;
    const int w = t >> 6, lane = t & 63;
    const int col = lane & 15, qd = lane >> 4;
    const int wm = w >> 1, wn = w & 1;
    const int m0 = blockIdx.x * 128, n0 = blockIdx.y * 128;

    __shared__ __align__(16) unsigned short As[128][40];
    __shared__ __align__(16) unsigned short Bs[128][40];

    floatx4 zero4 = {0.f, 0.f, 0.f, 0.f};
    floatx4 acc[4][4];          // [ct=channel tile][st=spatial tile]
    #pragma unroll
    for (int i = 0; i < 4; ++i)
        #pragma unroll
        for (int j = 0; j < 4; ++j) acc[i][j] = zero4;

    const int lrow = t >> 2, lc8 = (t & 3) * 8;

    // A from fp32 x (convert at LDS-store time), B from bf16 wT
    float4 a0, a1, a2, a3;
    ushort8 breg[2];
    a0 = *(const float4*)&x[(size_t)(m0 + lrow) * 256 + lc8];
    a1 = *(const float4*)&x[(size_t)(m0 + lrow) * 256 + lc8 + 4];
    a2 = *(const float4*)&x[(size_t)(m0 + lrow + 64) * 256 + lc8];
    a3 = *(const float4*)&x[(size_t)(m0 + lrow + 64) * 256 + lc8 + 4];
    breg[0] = *(const ushort8*)&wT[(size_t)(n0 + lrow) * 256 + lc8];
    breg[1] = *(const ushort8*)&wT[(size_t)(n0 + lrow + 64) * 256 + lc8];

    for (int kk = 0; kk < 8; ++kk) {
        __syncthreads();
        *(ushort8*)&As[lrow][lc8]      = cvt_bf8(a0, a1);
        *(ushort8*)&As[lrow + 64][lc8] = cvt_bf8(a2, a3);
        *(ushort8*)&Bs[lrow][lc8]      = breg[0];
        *(ushort8*)&Bs[lrow + 64][lc8] = breg[1];
        __syncthreads();
        const int kn = (kk < 7) ? (kk + 1) * 32 : 0;
        a0 = *(const float4*)&x[(size_t)(m0 + lrow) * 256 + kn + lc8];
        a1 = *(const float4*)&x[(size_t)(m0 + lrow) * 256 + kn + lc8 + 4];
        a2 = *(const float4*)&x[(size_t)(m0 + lrow + 64) * 256 + kn + lc8];
        a3 = *(const float4*)&x[(size_t)(m0 + lrow + 64) * 256 + kn + lc8 + 4];
        breg[0] = *(const ushort8*)&wT[(size_t)(n0 + lrow) * 256 + kn + lc8];
        breg[1] = *(const ushort8*)&wT[(size_t)(n0 + lrow + 64) * 256 + kn + lc8];

        bf16x8 wf[4];
        #pragma unroll
        for (int ct = 0; ct < 4; ++ct)
            wf[ct] = *(const bf16x8*)&Bs[wn * 64 + ct * 16 + col][qd * 8];
        #pragma unroll
        for (int st = 0; st < 4; ++st) {
            bf16x8 xf = *(const bf16x8*)&As[wm * 64 + st * 16 + col][qd * 8];
            #pragma unroll
            for (int ct = 0; ct < 4; ++ct)
                acc[ct][st] = __builtin_amdgcn_mfma_f32_16x16x32_bf16(wf[ct], xf, acc[ct][st], 0, 0, 0);
        }
    }

    #pragma unroll
    for (int ct = 0; ct < 4; ++ct) {
        const int cbase = n0 + wn * 64 + ct * 16;
        const int sect = cbase >> 9;
        const int hh = (cbase >> 6) & 7;
        const int dd = (cbase & 63) + qd * 4;
        if (sect < 2) {
            __bf16* base = (sect == 0) ? qb : kb;
            #pragma unroll
            for (int st = 0; st < 4; ++st) {
                const int m = m0 + wm * 64 + st * 16 + col;
                const int b_ = m >> 10, n = m & 1023;
                bf16x4 o;
                #pragma unroll
                for (int r = 0; r < 4; ++r) o[r] = (__bf16)acc[ct][st][r];
                *(bf16x4*)&base[(((size_t)b_ * HEADS + hh) * NPOS + n) * DH + dd] = o;
            }
        } else {
            #pragma unroll
            for (int st = 0; st < 4; ++st) {
                const int m = m0 + wm * 64 + st * 16 + col;
                const int b_ = m >> 10, n = m & 1023;
                const size_t rowbase = ((size_t)(b_ * HEADS + hh) * DH + dd) * NPOS + n;
                #pragma unroll
                for (int r = 0; r < 4; ++r)
                    vT[rowbase + (size_t)r * NPOS] = (__bf16)acc[ct][st][r];
            }
        }
    }
}

// ---------------- kernel B: flash attention, bf16 MFMA, TQ=128 ----------------
__global__ __launch_bounds__(256, 2) void attn_mfma(
    const __bf16* __restrict__ qg, const __bf16* __restrict__ kg,
    const __bf16* __restrict__ vTg, __bf16* __restrict__ o2tT)
{
    const int bid = blockIdx.x;
    const int qblk = bid & 7, h = (bid >> 3) & 7, b = bid >> 6;
    const int bh = b * HEADS + h;
    const int t = threadIdx.x;
    const int w = t >> 6, lane = t & 63;
    const int col = lane & 15;
    const int qd = lane >> 4;

    __shared__ __align__(16) unsigned short Ks[64][72];
    __shared__ __align__(16) unsigned short Vts[64][72];
    __shared__ __align__(16) unsigned short ps[4][32][68];  // reused as obuf[16][8][68]

    bf16x8 qf0[2], qf1[2];
    #pragma unroll
    for (int s = 0; s < 2; ++s) {
        const __bf16* qptr = qg + ((size_t)bh * NPOS + qblk * 128 + s * 64 + w * 16 + col) * DH;
        qf0[s] = *(const bf16x8*)(qptr + qd * 8);
        qf1[s] = *(const bf16x8*)(qptr + 32 + qd * 8);
    }

    const unsigned short* kbase  = (const unsigned short*)kg  + (size_t)bh * NPOS * DH;
    const unsigned short* vtbase = (const unsigned short*)vTg + (size_t)bh * DH * NPOS;

    const int r0 = t >> 3, c8 = (t & 7) * 8;

    ushort8 kreg[2], vreg[2];
    kreg[0] = *(const ushort8*)&kbase[(size_t)r0 * DH + c8];
    kreg[1] = *(const ushort8*)&kbase[(size_t)(r0 + 32) * DH + c8];
    vreg[0] = *(const ushort8*)&vtbase[(size_t)r0 * NPOS + c8];
    vreg[1] = *(const ushort8*)&vtbase[(size_t)(r0 + 32) * NPOS + c8];

    floatx4 zero4 = {0.f, 0.f, 0.f, 0.f};
    floatx4 accO[2][4];
    #pragma unroll
    for (int s = 0; s < 2; ++s)
        #pragma unroll
        for (int i = 0; i < 4; ++i) accO[s][i] = zero4;
    float lsum_acc[2] = {0.0f, 0.0f};

    for (int kt = 0; kt < 16; ++kt) {
        __syncthreads();
        *(ushort8*)&Ks[r0][c8]       = kreg[0];
        *(ushort8*)&Ks[r0 + 32][c8]  = kreg[1];
        *(ushort8*)&Vts[r0][c8]      = vreg[0];
        *(ushort8*)&Vts[r0 + 32][c8] = vreg[1];
        __syncthreads();

        const int ktn = (kt < 15) ? kt + 1 : 15;
        kreg[0] = *(const ushort8*)&kbase[(size_t)(ktn * 64 + r0) * DH + c8];
        kreg[1] = *(const ushort8*)&kbase[(size_t)(ktn * 64 + r0 + 32) * DH + c8];
        vreg[0] = *(const ushort8*)&vtbase[(size_t)r0 * NPOS + ktn * 64 + c8];
        vreg[1] = *(const ushort8*)&vtbase[(size_t)(r0 + 32) * NPOS + ktn * 64 + c8];

        floatx4 accS[2][4];
        #pragma unroll
        for (int mt = 0; mt < 4; ++mt) {
            bf16x8 kf0 = *(const bf16x8*)&Ks[mt * 16 + col][qd * 8];
            bf16x8 kf1 = *(const bf16x8*)&Ks[mt * 16 + col][32 + qd * 8];
            #pragma unroll
            for (int s = 0; s < 2; ++s) {
                accS[s][mt] = __builtin_amdgcn_mfma_f32_16x16x32_bf16(kf0, qf0[s], zero4, 0, 0, 0);
                accS[s][mt] = __builtin_amdgcn_mfma_f32_16x16x32_bf16(kf1, qf1[s], accS[s][mt], 0, 0, 0);
            }
        }

        #pragma unroll
        for (int s = 0; s < 2; ++s)
            #pragma unroll
            for (int mt = 0; mt < 4; ++mt) {
                bf16x4 pv;
                #pragma unroll
                for (int r = 0; r < 4; ++r) {
                    const float e = __expf(accS[s][mt][r]);
                    lsum_acc[s] += e;
                    pv[r] = (__bf16)e;
                }
                *(bf16x4*)&ps[w][s * 16 + col][mt * 16 + qd * 4] = pv;
            }

        bf16x8 pf0[2], pf1[2];
        #pragma unroll
        for (int s = 0; s < 2; ++s) {
            pf0[s] = *(const bf16x8*)&ps[w][s * 16 + col][qd * 8];
            pf1[s] = *(const bf16x8*)&ps[w][s * 16 + col][32 + qd * 8];
        }

        #pragma unroll
        for (int ct = 0; ct < 4; ++ct) {
            bf16x8 vf0 = *(const bf16x8*)&Vts[ct * 16 + col][qd * 8];
            bf16x8 vf1 = *(const bf16x8*)&Vts[ct * 16 + col][32 + qd * 8];
            #pragma unroll
            for (int s = 0; s < 2; ++s) {
                accO[s][ct] = __builtin_amdgcn_mfma_f32_16x16x32_bf16(vf0, pf0[s], accO[s][ct], 0, 0, 0);
                accO[s][ct] = __builtin_amdgcn_mfma_f32_16x16x32_bf16(vf1, pf1[s], accO[s][ct], 0, 0, 0);
            }
        }
    }

    float inv_l[2];
    #pragma unroll
    for (int s = 0; s < 2; ++s) {
        float l = lsum_acc[s];
        l += __shfl_xor(l, 16);
        l += __shfl_xor(l, 32);
        inv_l[s] = 1.0f / l;
    }

    unsigned short (*obuf)[8][68] = (unsigned short (*)[8][68])ps;
    __syncthreads();
    #pragma unroll
    for (int s = 0; s < 2; ++s)
        #pragma unroll
        for (int ct = 0; ct < 4; ++ct) {
            bf16x4 o;
            #pragma unroll
            for (int r = 0; r < 4; ++r) o[r] = (__bf16)(accO[s][ct][r] * inv_l[s]);
            *(bf16x4*)&obuf[col][s * 4 + w][ct * 16 + qd * 4] = o;
        }
    __syncthreads();
    const int chbase = h * 64 + qblk * 8;
    #pragma unroll
    for (int i = 0; i < 4; ++i) {
        const int p = i * 256 + t;
        const int pc = p >> 6, cc = p & 63;
        bf16x8 o;
        #pragma unroll
        for (int j = 0; j < 8; ++j) {
            unsigned short u = obuf[pc][j][cc];
            o[j] = *(__bf16*)&u;
        }
        *(bf16x8*)&o2tT[((size_t)b * NPOS + p) * ATTND + chbase] = o;
    }
}

// ---------------- kernel C: output GEMM + bias + fused GroupNorm (co-resident barrier) ----------------
// grid (128,4) = 512 blocks = exactly 2 blocks/CU (guaranteed co-resident:
// LDS 18.5 KB, VGPR < 128, __launch_bounds__(256,2)). After stats atomics each
// block spins on a device-scope counter, then normalizes its own registers.
__global__ __launch_bounds__(256, 2) void out_mfma_gn(
    const __bf16* __restrict__ a, const __bf16* __restrict__ woT,
    const float* __restrict__ b_out, const float* __restrict__ gamma,
    const float* __restrict__ beta, float* __restrict__ y,
    float* __restrict__ stats)
{
    const int t = threadIdx.x;
    const int w = t >> 6, lane = t & 63;
    const int col = lane & 15, qd = lane >> 4;
    const int wm = w >> 1, wn = w & 1;
    const int m0 = blockIdx.x * 64, d0 = blockIdx.y * 64;
    const int b = blockIdx.x >> 4;

    __shared__ __align__(16) unsigned short As[64][72];
    __shared__ __align__(16) unsigned short Bs[64][72];
    __shared__ float reds[4], redq[4];

    floatx4 zero4 = {0.f, 0.f, 0.f, 0.f};
    floatx4 acc[2][2];
    #pragma unroll
    for (int i = 0; i < 2; ++i)
        #pragma unroll
        for (int j = 0; j < 2; ++j) acc[i][j] = zero4;

    const int lrow = t >> 2, lc = (t & 3) * 16;

    for (int k0 = 0; k0 < ATTND; k0 += 64) {
        __syncthreads();
        *(ushort8*)&As[lrow][lc]     = *(const ushort8*)&a[(size_t)(m0 + lrow) * ATTND + k0 + lc];
        *(ushort8*)&As[lrow][lc + 8] = *(const ushort8*)&a[(size_t)(m0 + lrow) * ATTND + k0 + lc + 8];
        *(ushort8*)&Bs[lrow][lc]     = *(const ushort8*)&woT[(size_t)(d0 + lrow) * ATTND + k0 + lc];
        *(ushort8*)&Bs[lrow][lc + 8] = *(const ushort8*)&woT[(size_t)(d0 + lrow) * ATTND + k0 + lc + 8];
        __syncthreads();
        bf16x8 af0[2], af1[2];
        #pragma unroll
        for (int mt = 0; mt < 2; ++mt) {
            af0[mt] = *(const bf16x8*)&As[wm * 32 + mt * 16 + col][qd * 8];
            af1[mt] = *(const bf16x8*)&As[wm * 32 + mt * 16 + col][32 + qd * 8];
        }
        #pragma unroll
        for (int nt = 0; nt < 2; ++nt) {
            bf16x8 bf0 = *(const bf16x8*)&Bs[wn * 32 + nt * 16 + col][qd * 8];
            bf16x8 bf1 = *(const bf16x8*)&Bs[wn * 32 + nt * 16 + col][32 + qd * 8];
            #pragma unroll
            for (int mt = 0; mt < 2; ++mt) {
                acc[mt][nt] = __builtin_amdgcn_mfma_f32_16x16x32_bf16(af0[mt], bf0, acc[mt][nt], 0, 0, 0);
                acc[mt][nt] = __builtin_amdgcn_mfma_f32_16x16x32_bf16(af1[mt], bf1, acc[mt][nt], 0, 0, 0);
            }
        }
    }

    float bias_n[2], gam_n[2], bet_n[2];
    #pragma unroll
    for (int nt = 0; nt < 2; ++nt) {
        const int d = d0 + wn * 32 + nt * 16 + col;
        bias_n[nt] = b_out[d];
        gam_n[nt]  = gamma[d];
        bet_n[nt]  = beta[d];
    }

    // bias into acc + partial stats
    float bsum = 0.0f, bsq = 0.0f;
    #pragma unroll
    for (int mt = 0; mt < 2; ++mt)
        #pragma unroll
        for (int nt = 0; nt < 2; ++nt)
            #pragma unroll
            for (int r = 0; r < 4; ++r) {
                const float v = acc[mt][nt][r] + bias_n[nt];
                acc[mt][nt][r] = v;
                bsum += v;
                bsq  += v * v;
            }
    #pragma unroll
    for (int off = 1; off < 64; off <<= 1) {
        bsum += __shfl_xor(bsum, off);
        bsq  += __shfl_xor(bsq, off);
    }
    if (lane == 0) { reds[w] = bsum; redq[w] = bsq; }
    __syncthreads();

    int* cnt = (int*)(stats + 192);
    if (t == 0) {
        atomicAdd(&stats[b * 16],       reds[0] + reds[1] + reds[2] + reds[3]);
        atomicAdd(&stats[128 + b * 16], redq[0] + redq[1] + redq[2] + redq[3]);
        __threadfence();
        atomicAdd(cnt, 1);
        while (__hip_atomic_load(cnt, __ATOMIC_ACQUIRE, __HIP_MEMORY_SCOPE_AGENT) < 512) {}
        reds[0] = __hip_atomic_load(&stats[b * 16],       __ATOMIC_RELAXED, __HIP_MEMORY_SCOPE_AGENT);
        redq[0] = __hip_atomic_load(&stats[128 + b * 16], __ATOMIC_RELAXED, __HIP_MEMORY_SCOPE_AGENT);
    }
    __syncthreads();

    const float invn = 1.0f / (float)(NPOS * COUT);
    const float mean = reds[0] * invn;
    const float var  = redq[0] * invn - mean * mean;
    const float rsig = rsqrtf(var + GN_EPS);

    #pragma unroll
    for (int mt = 0; mt < 2; ++mt) {
        #pragma unroll
        for (int r = 0; r < 4; ++r) {
            const int m = m0 + wm * 32 + mt * 16 + qd * 4 + r;
            const int p = m & 1023;
            #pragma unroll
            for (int nt = 0; nt < 2; ++nt) {
                const int d = d0 + wn * 32 + nt * 16 + col;
                y[((size_t)b * NPOS + p) * COUT + d] =
                    (acc[mt][nt][r] - mean) * rsig * gam_n[nt] + bet_n[nt];
            }
        }
    }
}

extern "C" void kernel_launch(void* const* d_in, const int* in_sizes, int n_in,
                              void* d_out, int out_size, void* d_ws, size_t ws_size,
                              hipStream_t stream)
{
    const float* x     = (const float*)d_in[0];
    const float* w_qkv = (const float*)d_in[1];
    const float* w_out = (const float*)d_in[2];
    const float* b_out = (const float*)d_in[3];
    const float* gamma = (const float*)d_in[4];
    const float* beta  = (const float*)d_in[5];
    float* out = (float*)d_out;
    char* ws = (char*)d_ws;

    unsigned short* wT  = (unsigned short*)(ws + OFF_WT);
    unsigned short* woT = (unsigned short*)(ws + OFF_WOT);
    __bf16* qb  = (__bf16*)(ws + OFF_QB);
    __bf16* kb  = (__bf16*)(ws + OFF_KB);
    __bf16* vT  = (__bf16*)(ws + OFF_VT);
    __bf16* o2tT = (__bf16*)(ws + OFF_O2TT);
    float* stats = (float*)(ws + OFF_ST);

    prep         <<<dim3(128),    256, 0, stream>>>(w_qkv, w_out, wT, woT, stats);
    qkv_gemm_mfma<<<dim3(64, 12), 256, 0, stream>>>(x, (const __bf16*)wT, qb, kb, vT);
    attn_mfma    <<<dim3(512),    256, 0, stream>>>(qb, kb, vT, o2tT);
    out_mfma_gn  <<<dim3(128, 4), 256, 0, stream>>>(o2tT, (const __bf16*)woT, b_out, gamma, beta, out, stats);
}

// Round 11
// 128.011 us; speedup vs baseline: 1.1654x; 1.1654x over previous
//
#include <hip/hip_runtime.h>
#include <math.h>

#define NPOS   1024
#define CIN    256
#define DQKV   1536
#define ATTND  512
#define HEADS  8
#define DH     64
#define COUT   256
#define NBATCH 8
#define SCALE  0.125f
#define GN_EPS 1e-5f

typedef __attribute__((ext_vector_type(8))) __bf16 bf16x8;
typedef __attribute__((ext_vector_type(4))) __bf16 bf16x4;
typedef __attribute__((ext_vector_type(4))) float floatx4;
typedef __attribute__((ext_vector_type(8))) unsigned short ushort8;

// ws byte layout:
//   wT    bf16 [1536][256]          @ 4 MiB          (SCALE folded into cols<512)
//   woT   bf16 [256][512]           @ 4.75 MiB
//   qb    bf16 [B][H][1024][64]     @ 5 MiB
//   kb    bf16 same                 @ 13 MiB
//   vT    bf16 [B][H][64][1024]     @ 29 MiB         (written directly by qkv)
//   o2tT  bf16 [B][1024][512]       @ 45 MiB         (un-scrambled: [b][p][ch])
//   stats fp32 [256]                @ 53 MiB   sum[b]@b*16, sq[b]@128+b*16
#define OFF_WT   (4ull*1048576)
#define OFF_WOT  (4ull*1048576 + 786432ull)
#define OFF_QB   (5ull*1048576)
#define OFF_KB   (13ull*1048576)
#define OFF_VT   (29ull*1048576)
#define OFF_O2TT (45ull*1048576)
#define OFF_ST   (53ull*1048576)

__device__ inline ushort8 cvt_bf8(float4 a, float4 b) {
    bf16x8 o;
    o[0] = (__bf16)a.x; o[1] = (__bf16)a.y; o[2] = (__bf16)a.z; o[3] = (__bf16)a.w;
    o[4] = (__bf16)b.x; o[5] = (__bf16)b.y; o[6] = (__bf16)b.z; o[7] = (__bf16)b.w;
    return *(ushort8*)&o;
}

// ---------------- prep: weight conversions only (+ zero stats) ----------------
__global__ __launch_bounds__(256) void prep(
    const float* __restrict__ w_qkv, const float* __restrict__ w_out,
    unsigned short* __restrict__ wT, unsigned short* __restrict__ woT,
    float* __restrict__ stats)
{
    const int bid = blockIdx.x;
    const int t = threadIdx.x;
    __shared__ unsigned short tile[64][68];

    if (bid == 0) stats[t] = 0.0f;

    if (bid < 96) {
        const int n0 = (bid >> 2) * 64, k0 = (bid & 3) * 64;
        #pragma unroll
        for (int p = 0; p < 4; ++p) {
            const int row = p * 16 + (t >> 4);
            const int c = (t & 15) * 4;
            float4 a = *(const float4*)&w_qkv[(size_t)(k0 + row) * DQKV + n0 + c];
            float sv[4] = {a.x, a.y, a.z, a.w};
            #pragma unroll
            for (int j = 0; j < 4; ++j) {
                const float sc = (n0 + c + j) < 512 ? SCALE : 1.0f;
                __bf16 hb = (__bf16)(sv[j] * sc);
                tile[row][c + j] = *(unsigned short*)&hb;
            }
        }
        __syncthreads();
        const int nn = t >> 2;
        const int kc = (t & 3) * 16;
        unsigned short tmp[16];
        #pragma unroll
        for (int j = 0; j < 16; ++j) tmp[j] = tile[kc + j][nn];
        *(ushort8*)&wT[(size_t)(n0 + nn) * 256 + k0 + kc]     = *(ushort8*)&tmp[0];
        *(ushort8*)&wT[(size_t)(n0 + nn) * 256 + k0 + kc + 8] = *(ushort8*)&tmp[8];
        return;
    }

    const int idx = bid - 96;
    const int d0 = (idx & 3) * 64, k0 = (idx >> 2) * 64;
    #pragma unroll
    for (int p = 0; p < 4; ++p) {
        const int row = p * 16 + (t >> 4);
        const int c = (t & 15) * 4;
        float4 a = *(const float4*)&w_out[(size_t)(k0 + row) * COUT + d0 + c];
        float sv[4] = {a.x, a.y, a.z, a.w};
        #pragma unroll
        for (int j = 0; j < 4; ++j) {
            __bf16 hb = (__bf16)sv[j];
            tile[row][c + j] = *(unsigned short*)&hb;
        }
    }
    __syncthreads();
    {
        const int nn = t >> 2;
        const int kc = (t & 3) * 16;
        unsigned short tmp[16];
        #pragma unroll
        for (int j = 0; j < 16; ++j) tmp[j] = tile[kc + j][nn];
        *(ushort8*)&woT[(size_t)(d0 + nn) * 512 + k0 + kc]     = *(ushort8*)&tmp[0];
        *(ushort8*)&woT[(size_t)(d0 + nn) * 512 + k0 + kc + 8] = *(ushort8*)&tmp[8];
    }
}

// ---------------- kernel A: QKV GEMM, bf16 MFMA, fused x-conversion + V transpose ----------------
__global__ __launch_bounds__(256) void qkv_gemm_mfma(
    const float* __restrict__ x, const __bf16* __restrict__ wT,
    __bf16* __restrict__ qb, __bf16* __restrict__ kb, __bf16* __restrict__ vT)
{
    const int t = threadIdx.x;
    const int w = t >> 6, lane = t & 63;
    const int col = lane & 15, qd = lane >> 4;
    const int wm = w >> 1, wn = w & 1;
    const int m0 = blockIdx.x * 128, n0 = blockIdx.y * 128;

    __shared__ __align__(16) unsigned short As[128][40];
    __shared__ __align__(16) unsigned short Bs[128][40];

    floatx4 zero4 = {0.f, 0.f, 0.f, 0.f};
    floatx4 acc[4][4];
    #pragma unroll
    for (int i = 0; i < 4; ++i)
        #pragma unroll
        for (int j = 0; j < 4; ++j) acc[i][j] = zero4;

    const int lrow = t >> 2, lc8 = (t & 3) * 8;

    float4 a0, a1, a2, a3;
    ushort8 breg[2];
    a0 = *(const float4*)&x[(size_t)(m0 + lrow) * 256 + lc8];
    a1 = *(const float4*)&x[(size_t)(m0 + lrow) * 256 + lc8 + 4];
    a2 = *(const float4*)&x[(size_t)(m0 + lrow + 64) * 256 + lc8];
    a3 = *(const float4*)&x[(size_t)(m0 + lrow + 64) * 256 + lc8 + 4];
    breg[0] = *(const ushort8*)&wT[(size_t)(n0 + lrow) * 256 + lc8];
    breg[1] = *(const ushort8*)&wT[(size_t)(n0 + lrow + 64) * 256 + lc8];

    for (int kk = 0; kk < 8; ++kk) {
        __syncthreads();
        *(ushort8*)&As[lrow][lc8]      = cvt_bf8(a0, a1);
        *(ushort8*)&As[lrow + 64][lc8] = cvt_bf8(a2, a3);
        *(ushort8*)&Bs[lrow][lc8]      = breg[0];
        *(ushort8*)&Bs[lrow + 64][lc8] = breg[1];
        __syncthreads();
        const int kn = (kk < 7) ? (kk + 1) * 32 : 0;
        a0 = *(const float4*)&x[(size_t)(m0 + lrow) * 256 + kn + lc8];
        a1 = *(const float4*)&x[(size_t)(m0 + lrow) * 256 + kn + lc8 + 4];
        a2 = *(const float4*)&x[(size_t)(m0 + lrow + 64) * 256 + kn + lc8];
        a3 = *(const float4*)&x[(size_t)(m0 + lrow + 64) * 256 + kn + lc8 + 4];
        breg[0] = *(const ushort8*)&wT[(size_t)(n0 + lrow) * 256 + kn + lc8];
        breg[1] = *(const ushort8*)&wT[(size_t)(n0 + lrow + 64) * 256 + kn + lc8];

        bf16x8 wf[4];
        #pragma unroll
        for (int ct = 0; ct < 4; ++ct)
            wf[ct] = *(const bf16x8*)&Bs[wn * 64 + ct * 16 + col][qd * 8];
        #pragma unroll
        for (int st = 0; st < 4; ++st) {
            bf16x8 xf = *(const bf16x8*)&As[wm * 64 + st * 16 + col][qd * 8];
            #pragma unroll
            for (int ct = 0; ct < 4; ++ct)
                acc[ct][st] = __builtin_amdgcn_mfma_f32_16x16x32_bf16(wf[ct], xf, acc[ct][st], 0, 0, 0);
        }
    }

    #pragma unroll
    for (int ct = 0; ct < 4; ++ct) {
        const int cbase = n0 + wn * 64 + ct * 16;
        const int sect = cbase >> 9;
        const int hh = (cbase >> 6) & 7;
        const int dd = (cbase & 63) + qd * 4;
        if (sect < 2) {
            __bf16* base = (sect == 0) ? qb : kb;
            #pragma unroll
            for (int st = 0; st < 4; ++st) {
                const int m = m0 + wm * 64 + st * 16 + col;
                const int b_ = m >> 10, n = m & 1023;
                bf16x4 o;
                #pragma unroll
                for (int r = 0; r < 4; ++r) o[r] = (__bf16)acc[ct][st][r];
                *(bf16x4*)&base[(((size_t)b_ * HEADS + hh) * NPOS + n) * DH + dd] = o;
            }
        } else {
            #pragma unroll
            for (int st = 0; st < 4; ++st) {
                const int m = m0 + wm * 64 + st * 16 + col;
                const int b_ = m >> 10, n = m & 1023;
                const size_t rowbase = ((size_t)(b_ * HEADS + hh) * DH + dd) * NPOS + n;
                #pragma unroll
                for (int r = 0; r < 4; ++r)
                    vT[rowbase + (size_t)r * NPOS] = (__bf16)acc[ct][st][r];
            }
        }
    }
}

// ---------------- kernel B: flash attention, bf16 MFMA, TQ=128 ----------------
__global__ __launch_bounds__(256, 2) void attn_mfma(
    const __bf16* __restrict__ qg, const __bf16* __restrict__ kg,
    const __bf16* __restrict__ vTg, __bf16* __restrict__ o2tT)
{
    const int bid = blockIdx.x;
    const int qblk = bid & 7, h = (bid >> 3) & 7, b = bid >> 6;
    const int bh = b * HEADS + h;
    const int t = threadIdx.x;
    const int w = t >> 6, lane = t & 63;
    const int col = lane & 15;
    const int qd = lane >> 4;

    __shared__ __align__(16) unsigned short Ks[64][72];
    __shared__ __align__(16) unsigned short Vts[64][72];
    __shared__ __align__(16) unsigned short ps[4][32][68];  // reused as obuf[16][8][68]

    bf16x8 qf0[2], qf1[2];
    #pragma unroll
    for (int s = 0; s < 2; ++s) {
        const __bf16* qptr = qg + ((size_t)bh * NPOS + qblk * 128 + s * 64 + w * 16 + col) * DH;
        qf0[s] = *(const bf16x8*)(qptr + qd * 8);
        qf1[s] = *(const bf16x8*)(qptr + 32 + qd * 8);
    }

    const unsigned short* kbase  = (const unsigned short*)kg  + (size_t)bh * NPOS * DH;
    const unsigned short* vtbase = (const unsigned short*)vTg + (size_t)bh * DH * NPOS;

    const int r0 = t >> 3, c8 = (t & 7) * 8;

    ushort8 kreg[2], vreg[2];
    kreg[0] = *(const ushort8*)&kbase[(size_t)r0 * DH + c8];
    kreg[1] = *(const ushort8*)&kbase[(size_t)(r0 + 32) * DH + c8];
    vreg[0] = *(const ushort8*)&vtbase[(size_t)r0 * NPOS + c8];
    vreg[1] = *(const ushort8*)&vtbase[(size_t)(r0 + 32) * NPOS + c8];

    floatx4 zero4 = {0.f, 0.f, 0.f, 0.f};
    floatx4 accO[2][4];
    #pragma unroll
    for (int s = 0; s < 2; ++s)
        #pragma unroll
        for (int i = 0; i < 4; ++i) accO[s][i] = zero4;
    float lsum_acc[2] = {0.0f, 0.0f};

    for (int kt = 0; kt < 16; ++kt) {
        __syncthreads();
        *(ushort8*)&Ks[r0][c8]       = kreg[0];
        *(ushort8*)&Ks[r0 + 32][c8]  = kreg[1];
        *(ushort8*)&Vts[r0][c8]      = vreg[0];
        *(ushort8*)&Vts[r0 + 32][c8] = vreg[1];
        __syncthreads();

        const int ktn = (kt < 15) ? kt + 1 : 15;
        kreg[0] = *(const ushort8*)&kbase[(size_t)(ktn * 64 + r0) * DH + c8];
        kreg[1] = *(const ushort8*)&kbase[(size_t)(ktn * 64 + r0 + 32) * DH + c8];
        vreg[0] = *(const ushort8*)&vtbase[(size_t)r0 * NPOS + ktn * 64 + c8];
        vreg[1] = *(const ushort8*)&vtbase[(size_t)(r0 + 32) * NPOS + ktn * 64 + c8];

        floatx4 accS[2][4];
        #pragma unroll
        for (int mt = 0; mt < 4; ++mt) {
            bf16x8 kf0 = *(const bf16x8*)&Ks[mt * 16 + col][qd * 8];
            bf16x8 kf1 = *(const bf16x8*)&Ks[mt * 16 + col][32 + qd * 8];
            #pragma unroll
            for (int s = 0; s < 2; ++s) {
                accS[s][mt] = __builtin_amdgcn_mfma_f32_16x16x32_bf16(kf0, qf0[s], zero4, 0, 0, 0);
                accS[s][mt] = __builtin_amdgcn_mfma_f32_16x16x32_bf16(kf1, qf1[s], accS[s][mt], 0, 0, 0);
            }
        }

        #pragma unroll
        for (int s = 0; s < 2; ++s)
            #pragma unroll
            for (int mt = 0; mt < 4; ++mt) {
                bf16x4 pv;
                #pragma unroll
                for (int r = 0; r < 4; ++r) {
                    const float e = __expf(accS[s][mt][r]);
                    lsum_acc[s] += e;
                    pv[r] = (__bf16)e;
                }
                *(bf16x4*)&ps[w][s * 16 + col][mt * 16 + qd * 4] = pv;
            }

        bf16x8 pf0[2], pf1[2];
        #pragma unroll
        for (int s = 0; s < 2; ++s) {
            pf0[s] = *(const bf16x8*)&ps[w][s * 16 + col][qd * 8];
            pf1[s] = *(const bf16x8*)&ps[w][s * 16 + col][32 + qd * 8];
        }

        #pragma unroll
        for (int ct = 0; ct < 4; ++ct) {
            bf16x8 vf0 = *(const bf16x8*)&Vts[ct * 16 + col][qd * 8];
            bf16x8 vf1 = *(const bf16x8*)&Vts[ct * 16 + col][32 + qd * 8];
            #pragma unroll
            for (int s = 0; s < 2; ++s) {
                accO[s][ct] = __builtin_amdgcn_mfma_f32_16x16x32_bf16(vf0, pf0[s], accO[s][ct], 0, 0, 0);
                accO[s][ct] = __builtin_amdgcn_mfma_f32_16x16x32_bf16(vf1, pf1[s], accO[s][ct], 0, 0, 0);
            }
        }
    }

    float inv_l[2];
    #pragma unroll
    for (int s = 0; s < 2; ++s) {
        float l = lsum_acc[s];
        l += __shfl_xor(l, 16);
        l += __shfl_xor(l, 32);
        inv_l[s] = 1.0f / l;
    }

    unsigned short (*obuf)[8][68] = (unsigned short (*)[8][68])ps;
    __syncthreads();
    #pragma unroll
    for (int s = 0; s < 2; ++s)
        #pragma unroll
        for (int ct = 0; ct < 4; ++ct) {
            bf16x4 o;
            #pragma unroll
            for (int r = 0; r < 4; ++r) o[r] = (__bf16)(accO[s][ct][r] * inv_l[s]);
            *(bf16x4*)&obuf[col][s * 4 + w][ct * 16 + qd * 4] = o;
        }
    __syncthreads();
    const int chbase = h * 64 + qblk * 8;
    #pragma unroll
    for (int i = 0; i < 4; ++i) {
        const int p = i * 256 + t;
        const int pc = p >> 6, cc = p & 63;
        bf16x8 o;
        #pragma unroll
        for (int j = 0; j < 8; ++j) {
            unsigned short u = obuf[pc][j][cc];
            o[j] = *(__bf16*)&u;
        }
        *(bf16x8*)&o2tT[((size_t)b * NPOS + p) * ATTND + chbase] = o;
    }
}

// ---------------- kernel C: output GEMM, bf16 MFMA + bias + GN stats (round-9 proven) ----------------
__global__ __launch_bounds__(256) void out_mfma(
    const __bf16* __restrict__ a, const __bf16* __restrict__ woT,
    const float* __restrict__ b_out, float* __restrict__ y,
    float* __restrict__ stats)
{
    const int t = threadIdx.x;
    const int w = t >> 6, lane = t & 63;
    const int col = lane & 15, qd = lane >> 4;
    const int wm = w >> 1, wn = w & 1;
    const int m0 = blockIdx.x * 64, d0 = blockIdx.y * 64;
    const int b = blockIdx.x >> 4;

    __shared__ __align__(16) unsigned short As[64][72];
    __shared__ __align__(16) unsigned short Bs[64][72];
    __shared__ float reds[4], redq[4];

    floatx4 zero4 = {0.f, 0.f, 0.f, 0.f};
    floatx4 acc[2][2];
    #pragma unroll
    for (int i = 0; i < 2; ++i)
        #pragma unroll
        for (int j = 0; j < 2; ++j) acc[i][j] = zero4;

    const int lrow = t >> 2, lc = (t & 3) * 16;

    for (int k0 = 0; k0 < ATTND; k0 += 64) {
        __syncthreads();
        *(ushort8*)&As[lrow][lc]     = *(const ushort8*)&a[(size_t)(m0 + lrow) * ATTND + k0 + lc];
        *(ushort8*)&As[lrow][lc + 8] = *(const ushort8*)&a[(size_t)(m0 + lrow) * ATTND + k0 + lc + 8];
        *(ushort8*)&Bs[lrow][lc]     = *(const ushort8*)&woT[(size_t)(d0 + lrow) * ATTND + k0 + lc];
        *(ushort8*)&Bs[lrow][lc + 8] = *(const ushort8*)&woT[(size_t)(d0 + lrow) * ATTND + k0 + lc + 8];
        __syncthreads();
        bf16x8 af0[2], af1[2];
        #pragma unroll
        for (int mt = 0; mt < 2; ++mt) {
            af0[mt] = *(const bf16x8*)&As[wm * 32 + mt * 16 + col][qd * 8];
            af1[mt] = *(const bf16x8*)&As[wm * 32 + mt * 16 + col][32 + qd * 8];
        }
        #pragma unroll
        for (int nt = 0; nt < 2; ++nt) {
            bf16x8 bf0 = *(const bf16x8*)&Bs[wn * 32 + nt * 16 + col][qd * 8];
            bf16x8 bf1 = *(const bf16x8*)&Bs[wn * 32 + nt * 16 + col][32 + qd * 8];
            #pragma unroll
            for (int mt = 0; mt < 2; ++mt) {
                acc[mt][nt] = __builtin_amdgcn_mfma_f32_16x16x32_bf16(af0[mt], bf0, acc[mt][nt], 0, 0, 0);
                acc[mt][nt] = __builtin_amdgcn_mfma_f32_16x16x32_bf16(af1[mt], bf1, acc[mt][nt], 0, 0, 0);
            }
        }
    }

    float bias_n[2];
    #pragma unroll
    for (int nt = 0; nt < 2; ++nt) bias_n[nt] = b_out[d0 + wn * 32 + nt * 16 + col];

    float bsum = 0.0f, bsq = 0.0f;
    #pragma unroll
    for (int mt = 0; mt < 2; ++mt) {
        #pragma unroll
        for (int r = 0; r < 4; ++r) {
            const int m = m0 + wm * 32 + mt * 16 + qd * 4 + r;
            const int p = m & 1023;
            #pragma unroll
            for (int nt = 0; nt < 2; ++nt) {
                const int d = d0 + wn * 32 + nt * 16 + col;
                const float v = acc[mt][nt][r] + bias_n[nt];
                y[((size_t)b * NPOS + p) * COUT + d] = v;
                bsum += v;
                bsq  += v * v;
            }
        }
    }
    #pragma unroll
    for (int off = 1; off < 64; off <<= 1) {
        bsum += __shfl_xor(bsum, off);
        bsq  += __shfl_xor(bsq, off);
    }
    if (lane == 0) { reds[w] = bsum; redq[w] = bsq; }
    __syncthreads();
    if (t == 0) {
        atomicAdd(&stats[b * 16],       reds[0] + reds[1] + reds[2] + reds[3]);
        atomicAdd(&stats[128 + b * 16], redq[0] + redq[1] + redq[2] + redq[3]);
    }
}

// ---------------- kernel D: GroupNorm finalize ----------------
__global__ __launch_bounds__(256) void gn_finalize(
    float* __restrict__ y, const float* __restrict__ stats,
    const float* __restrict__ gamma, const float* __restrict__ beta)
{
    const int idx = blockIdx.x * 256 + threadIdx.x;
    const int e = idx * 4;
    const int b_ = e >> 18;
    const int d = e & (COUT - 1);
    const float invn = 1.0f / (float)(NPOS * COUT);
    const float mean = stats[b_ * 16] * invn;
    const float var  = stats[128 + b_ * 16] * invn - mean * mean;
    const float rsig = rsqrtf(var + GN_EPS);
    float4 vv = *(float4*)&y[e];
    const float4 g  = *(const float4*)&gamma[d];
    const float4 bt = *(const float4*)&beta[d];
    vv.x = (vv.x - mean) * rsig * g.x + bt.x;
    vv.y = (vv.y - mean) * rsig * g.y + bt.y;
    vv.z = (vv.z - mean) * rsig * g.z + bt.z;
    vv.w = (vv.w - mean) * rsig * g.w + bt.w;
    *(float4*)&y[e] = vv;
}

extern "C" void kernel_launch(void* const* d_in, const int* in_sizes, int n_in,
                              void* d_out, int out_size, void* d_ws, size_t ws_size,
                              hipStream_t stream)
{
    const float* x     = (const float*)d_in[0];
    const float* w_qkv = (const float*)d_in[1];
    const float* w_out = (const float*)d_in[2];
    const float* b_out = (const float*)d_in[3];
    const float* gamma = (const float*)d_in[4];
    const float* beta  = (const float*)d_in[5];
    float* out = (float*)d_out;
    char* ws = (char*)d_ws;

    unsigned short* wT  = (unsigned short*)(ws + OFF_WT);
    unsigned short* woT = (unsigned short*)(ws + OFF_WOT);
    __bf16* qb  = (__bf16*)(ws + OFF_QB);
    __bf16* kb  = (__bf16*)(ws + OFF_KB);
    __bf16* vT  = (__bf16*)(ws + OFF_VT);
    __bf16* o2tT = (__bf16*)(ws + OFF_O2TT);
    float* stats = (float*)(ws + OFF_ST);

    prep         <<<dim3(128),    256, 0, stream>>>(w_qkv, w_out, wT, woT, stats);
    qkv_gemm_mfma<<<dim3(64, 12), 256, 0, stream>>>(x, (const __bf16*)wT, qb, kb, vT);
    attn_mfma    <<<dim3(512),    256, 0, stream>>>(qb, kb, vT, o2tT);
    out_mfma     <<<dim3(128, 4), 256, 0, stream>>>(o2tT, (const __bf16*)woT, b_out, out, stats);
    gn_finalize  <<<dim3(2048),   256, 0, stream>>>(out, stats, gamma, beta);
}